// Round 1
// baseline (436.968 us; speedup 1.0000x reference)
//
#include <hip/hip_runtime.h>
#include <math.h>

#define NN 4096
#define CC 256
#define HH 8
#define DD 32
#define EE 65536

typedef unsigned short u16;
typedef unsigned int u32;
typedef unsigned long long u64;

typedef float f32x4 __attribute__((ext_vector_type(4)));
typedef __bf16 bf16x8 __attribute__((ext_vector_type(8)));

__device__ __forceinline__ u16 f2b(float f){
  u32 u = __float_as_uint(f);
  return (u16)((u + 0x7FFFu + ((u >> 16) & 1u)) >> 16);
}

// ---------------- graph: degree, CSR ----------------
__global__ __launch_bounds__(256) void k_deg(const int* __restrict__ ei, int* __restrict__ deg){
  int e = blockIdx.x * 256 + threadIdx.x;
  if (e < EE){
    atomicAdd(&deg[ei[e]], 1);
    atomicAdd(&deg[ei[EE + e]], 1);
  }
}

__global__ __launch_bounds__(256) void k_scan(const int* __restrict__ deg, int* __restrict__ rowp,
                                              int* __restrict__ cur){
  __shared__ int part[256];
  int t = threadIdx.x;
  int local[16];
  int s = 0;
  #pragma unroll
  for (int i = 0; i < 16; i++){ local[i] = s; s += deg[t*16 + i]; }
  part[t] = s;
  __syncthreads();
  for (int off = 1; off < 256; off <<= 1){
    int v = (t >= off) ? part[t - off] : 0;
    __syncthreads();
    part[t] += v;
    __syncthreads();
  }
  int excl = (t == 0) ? 0 : part[t - 1];
  #pragma unroll
  for (int i = 0; i < 16; i++){ int v = excl + local[i]; rowp[t*16+i] = v; cur[t*16+i] = v; }
  if (t == 255) rowp[4096] = excl + s;
}

__global__ __launch_bounds__(256) void k_fill(const int* __restrict__ ei, int* __restrict__ cur,
                                              int* __restrict__ col){
  int e = blockIdx.x * 256 + threadIdx.x;
  if (e < EE){
    int r = ei[e], c = ei[EE + e];
    col[atomicAdd(&cur[r], 1)] = c;
    col[atomicAdd(&cur[c], 1)] = r;
  }
}

// ---------------- hidden = x + deg_emb[min(deg,33)] (bf16) ----------------
__global__ __launch_bounds__(256) void k_hidden(const float* __restrict__ x, const float* __restrict__ demb,
                                                const int* __restrict__ deg, u16* __restrict__ hb){
  int i = blockIdx.x * 256 + threadIdx.x;
  int n = i >> 8, c = i & 255;
  int d = deg[n]; if (d > 33) d = 33;
  hb[i] = f2b(x[i] + demb[d * CC + c]);
}

// ---------------- bit-parallel BFS ----------------
__global__ __launch_bounds__(256) void k_b0(u64* __restrict__ B0){
  int i = blockIdx.x * 256 + threadIdx.x;
  int j = i >> 6, w = i & 63;
  B0[i] = (w == (j >> 6)) ? (1ull << (j & 63)) : 0ull;
}

__global__ __launch_bounds__(256) void k_prop(const u64* __restrict__ Bp, u64* __restrict__ Bn,
                                              const int* __restrict__ rowp, const int* __restrict__ col){
  int i = blockIdx.x * 256 + threadIdx.x;
  int j = i >> 6, w = i & 63;   // one wave per node j, lane = word w
  u64 acc = Bp[i];
  int s = rowp[j], e = rowp[j + 1];
  for (int p = s; p < e; p++){
    acc |= Bp[(col[p] << 6) + w];
  }
  Bn[i] = acc;
}

__global__ __launch_bounds__(256) void k_dist(const u64* __restrict__ B1, const u64* __restrict__ B2,
                                              const u64* __restrict__ B3, const u64* __restrict__ B4,
                                              unsigned char* __restrict__ dist){
  int i = blockIdx.x * 256 + threadIdx.x;
  int j = i >> 6, w = i & 63;
  u64 b1 = B1[i], b2 = B2[i], b3 = B3[i], b4 = B4[i];
  u32 ob[16];
  #pragma unroll
  for (int g = 0; g < 16; g++){
    u32 word = 0;
    #pragma unroll
    for (int q = 0; q < 4; q++){
      int bit = g * 4 + q;
      u32 d;
      if ((b1 >> bit) & 1) d = 1;
      else if ((b2 >> bit) & 1) d = 2;
      else if ((b3 >> bit) & 1) d = 3;
      else if ((b4 >> bit) & 1) d = 4;
      else d = 5;
      if ((w << 6) + bit == j) d = 0;
      word |= d << (q * 8);
    }
    ob[g] = word;
  }
  uint4* dp = (uint4*)(dist + ((size_t)j << 12) + (w << 6));
  uint4* ov = (uint4*)ob;
  dp[0] = ov[0]; dp[1] = ov[1]; dp[2] = ov[2]; dp[3] = ov[3];
}

// ---------------- weight convert: fp32 [K][N] -> bf16 transposed [N][K] ----------------
__global__ __launch_bounds__(256) void k_wconv(const float* __restrict__ W, u16* __restrict__ Wt,
                                               int K, int N){
  int i = blockIdx.x * 256 + threadIdx.x;
  if (i < K * N){
    int n = i / K, k = i - n * K;
    Wt[i] = f2b(W[k * N + n]);
  }
}

// ---------------- bf16 MFMA GEMM: out = A[M][K] @ Wt^T + bias ----------------
// mode: 1 = f32 out [M][N]; 2 = bf16 out [M][N]; 4 = bf16 out transposed [N][M]; 8 = exact GELU
__global__ __launch_bounds__(256) void k_gemm(const u16* __restrict__ A, const u16* __restrict__ Wt,
                                              const float* __restrict__ bias,
                                              float* __restrict__ outF, u16* __restrict__ outB,
                                              int M, int N, int K, int mode){
  __shared__ __align__(16) u16 As[64][40];
  __shared__ __align__(16) u16 Bs[64][40];
  int t = threadIdx.x;
  int lane = t & 63;
  int wv = t >> 6;
  int wm = wv >> 1, wn = wv & 1;
  int m0 = blockIdx.x * 64, n0 = blockIdx.y * 64;
  int lr = t >> 2;            // staging row 0..63
  int lk = (t & 3) * 8;       // staging k-chunk
  int row16 = lane & 15, kq = (lane >> 4) * 8;
  f32x4 zero = {0.f, 0.f, 0.f, 0.f};
  f32x4 acc[2][2] = {{zero, zero}, {zero, zero}};
  for (int k0 = 0; k0 < K; k0 += 32){
    __syncthreads();
    *(bf16x8*)&As[lr][lk] = *(const bf16x8*)&A [(size_t)(m0 + lr) * K + k0 + lk];
    *(bf16x8*)&Bs[lr][lk] = *(const bf16x8*)&Wt[(size_t)(n0 + lr) * K + k0 + lk];
    __syncthreads();
    bf16x8 a0 = *(const bf16x8*)&As[wm*32 +      row16][kq];
    bf16x8 a1 = *(const bf16x8*)&As[wm*32 + 16 + row16][kq];
    bf16x8 b0 = *(const bf16x8*)&Bs[wn*32 +      row16][kq];
    bf16x8 b1 = *(const bf16x8*)&Bs[wn*32 + 16 + row16][kq];
    acc[0][0] = __builtin_amdgcn_mfma_f32_16x16x32_bf16(a0, b0, acc[0][0], 0, 0, 0);
    acc[0][1] = __builtin_amdgcn_mfma_f32_16x16x32_bf16(a0, b1, acc[0][1], 0, 0, 0);
    acc[1][0] = __builtin_amdgcn_mfma_f32_16x16x32_bf16(a1, b0, acc[1][0], 0, 0, 0);
    acc[1][1] = __builtin_amdgcn_mfma_f32_16x16x32_bf16(a1, b1, acc[1][1], 0, 0, 0);
  }
  int rg = (lane >> 4) * 4;
  #pragma unroll
  for (int fm = 0; fm < 2; fm++)
    #pragma unroll
    for (int fn = 0; fn < 2; fn++){
      int gn = n0 + wn*32 + fn*16 + row16;
      float bv = bias[gn];
      #pragma unroll
      for (int r = 0; r < 4; r++){
        int gm = m0 + wm*32 + fm*16 + rg + r;
        float v = acc[fm][fn][r] + bv;
        if (mode & 8) v = 0.5f * v * (1.0f + erff(v * 0.70710678118654752f));
        if (mode & 1) outF[(size_t)gm * N + gn] = v;
        if (mode & 2) outB[(size_t)gm * N + gn] = f2b(v);
        if (mode & 4) outB[(size_t)gn * M + gm] = f2b(v);
      }
    }
}

// ---------------- flash attention with spatial bias ----------------
// WG: 32 queries x 4 heads (1 head per wave). Loops 64-key tiles.
__global__ __launch_bounds__(256) void k_attn(const u16* __restrict__ qg, const u16* __restrict__ kg,
                                              const u16* __restrict__ vtg,
                                              const unsigned char* __restrict__ dist,
                                              const float* __restrict__ spa, u16* __restrict__ attb){
  __shared__ __align__(16) u16 P[4][32][72];
  __shared__ __align__(16) unsigned char dls[32][64];
  __shared__ float spas[48];
  int t = threadIdx.x;
  int lane = t & 63;
  int wv = t >> 6;
  int h = blockIdx.y * 4 + wv;
  int q0 = blockIdx.x * 32;
  if (t < 48) spas[t] = spa[t];
  int row16 = lane & 15;
  int kq = (lane >> 4) * 8;
  int rg = (lane >> 4) * 4;
  bf16x8 qf0 = *(const bf16x8*)&qg[(size_t)(q0 +      row16) * CC + h * DD + kq];
  bf16x8 qf1 = *(const bf16x8*)&qg[(size_t)(q0 + 16 + row16) * CC + h * DD + kq];
  f32x4 zero = {0.f, 0.f, 0.f, 0.f};
  f32x4 acc[2][2] = {{zero, zero}, {zero, zero}};
  float ms[2][4], ls[2][4];
  #pragma unroll
  for (int a = 0; a < 2; a++)
    #pragma unroll
    for (int r = 0; r < 4; r++){ ms[a][r] = -INFINITY; ls[a][r] = 0.f; }
  const float scale = 0.17677669529663687f; // 1/sqrt(32)
  int drow = t >> 3, dcol = (t & 7) * 8;

  for (int kt = 0; kt < NN; kt += 64){
    __syncthreads();
    *(uint2*)&dls[drow][dcol] = *(const uint2*)&dist[(size_t)(q0 + drow) * NN + kt + dcol];
    __syncthreads();
    // QK^T
    f32x4 sc[2][4];
    #pragma unroll
    for (int fn = 0; fn < 4; fn++){
      bf16x8 kf = *(const bf16x8*)&kg[(size_t)(kt + fn*16 + row16) * CC + h * DD + kq];
      sc[0][fn] = __builtin_amdgcn_mfma_f32_16x16x32_bf16(qf0, kf, zero, 0, 0, 0);
      sc[1][fn] = __builtin_amdgcn_mfma_f32_16x16x32_bf16(qf1, kf, zero, 0, 0, 0);
    }
    // scale + spatial bias + row tile-max
    float tmax[2][4];
    #pragma unroll
    for (int a = 0; a < 2; a++)
      #pragma unroll
      for (int r = 0; r < 4; r++) tmax[a][r] = -INFINITY;
    #pragma unroll
    for (int fm = 0; fm < 2; fm++)
      #pragma unroll
      for (int fn = 0; fn < 4; fn++)
        #pragma unroll
        for (int r = 0; r < 4; r++){
          int b = dls[fm*16 + rg + r][fn*16 + row16];
          float v = sc[fm][fn][r] * scale + spas[b * 8 + h];
          sc[fm][fn][r] = v;
          tmax[fm][r] = fmaxf(tmax[fm][r], v);
        }
    #pragma unroll
    for (int m = 1; m < 16; m <<= 1)
      #pragma unroll
      for (int fm = 0; fm < 2; fm++)
        #pragma unroll
        for (int r = 0; r < 4; r++)
          tmax[fm][r] = fmaxf(tmax[fm][r], __shfl_xor(tmax[fm][r], m, 64));
    float scl[2][4], rsum[2][4];
    #pragma unroll
    for (int fm = 0; fm < 2; fm++)
      #pragma unroll
      for (int r = 0; r < 4; r++){
        float nm = fmaxf(ms[fm][r], tmax[fm][r]);
        scl[fm][r] = __expf(ms[fm][r] - nm);
        ms[fm][r] = nm;
        rsum[fm][r] = 0.f;
      }
    // P = exp(s - m), store bf16 to LDS
    #pragma unroll
    for (int fm = 0; fm < 2; fm++)
      #pragma unroll
      for (int fn = 0; fn < 4; fn++)
        #pragma unroll
        for (int r = 0; r < 4; r++){
          float p = __expf(sc[fm][fn][r] - ms[fm][r]);
          rsum[fm][r] += p;
          P[wv][fm*16 + rg + r][fn*16 + row16] = f2b(p);
        }
    #pragma unroll
    for (int m = 1; m < 16; m <<= 1)
      #pragma unroll
      for (int fm = 0; fm < 2; fm++)
        #pragma unroll
        for (int r = 0; r < 4; r++)
          rsum[fm][r] += __shfl_xor(rsum[fm][r], m, 64);
    #pragma unroll
    for (int fm = 0; fm < 2; fm++)
      #pragma unroll
      for (int r = 0; r < 4; r++)
        ls[fm][r] = ls[fm][r] * scl[fm][r] + rsum[fm][r];
    #pragma unroll
    for (int fm = 0; fm < 2; fm++)
      #pragma unroll
      for (int fd = 0; fd < 2; fd++)
        #pragma unroll
        for (int r = 0; r < 4; r++)
          acc[fm][fd][r] *= scl[fm][r];
    // PV
    #pragma unroll
    for (int ks = 0; ks < 2; ks++){
      bf16x8 pa0 = *(const bf16x8*)&P[wv][     row16][ks*32 + kq];
      bf16x8 pa1 = *(const bf16x8*)&P[wv][16 + row16][ks*32 + kq];
      #pragma unroll
      for (int fd = 0; fd < 2; fd++){
        bf16x8 vf = *(const bf16x8*)&vtg[(size_t)(h*DD + fd*16 + row16) * NN + kt + ks*32 + kq];
        acc[0][fd] = __builtin_amdgcn_mfma_f32_16x16x32_bf16(pa0, vf, acc[0][fd], 0, 0, 0);
        acc[1][fd] = __builtin_amdgcn_mfma_f32_16x16x32_bf16(pa1, vf, acc[1][fd], 0, 0, 0);
      }
    }
  }
  #pragma unroll
  for (int fm = 0; fm < 2; fm++)
    #pragma unroll
    for (int fd = 0; fd < 2; fd++)
      #pragma unroll
      for (int r = 0; r < 4; r++){
        float v = acc[fm][fd][r] / ls[fm][r];
        attb[(size_t)(q0 + fm*16 + rg + r) * CC + h*DD + fd*16 + row16] = f2b(v);
      }
}

// ---------------- residual + LayerNorm (wave per row) ----------------
__global__ __launch_bounds__(256) void k_ln(const float* __restrict__ ina, const float* __restrict__ inb,
                                            const float* __restrict__ g, const float* __restrict__ b,
                                            float* __restrict__ outF, u16* __restrict__ outB){
  int t = threadIdx.x;
  int wv = t >> 6, lane = t & 63;
  int row = blockIdx.x * 4 + wv;
  size_t base = (size_t)row * CC + lane * 4;
  float4 xa = *(const float4*)&ina[base];
  float4 xb = *(const float4*)&inb[base];
  float v0 = xa.x + xb.x, v1 = xa.y + xb.y, v2 = xa.z + xb.z, v3 = xa.w + xb.w;
  float s  = v0 + v1 + v2 + v3;
  float s2 = v0*v0 + v1*v1 + v2*v2 + v3*v3;
  #pragma unroll
  for (int m = 1; m < 64; m <<= 1){
    s  += __shfl_xor(s,  m, 64);
    s2 += __shfl_xor(s2, m, 64);
  }
  float mu  = s * (1.0f / 256.0f);
  float var = s2 * (1.0f / 256.0f) - mu * mu;
  float rs  = rsqrtf(var + 1e-5f);
  float4 gv = *(const float4*)&g[lane * 4];
  float4 bv = *(const float4*)&b[lane * 4];
  float o0 = (v0 - mu) * rs * gv.x + bv.x;
  float o1 = (v1 - mu) * rs * gv.y + bv.y;
  float o2 = (v2 - mu) * rs * gv.z + bv.z;
  float o3 = (v3 - mu) * rs * gv.w + bv.w;
  if (outF){ float4 o = {o0, o1, o2, o3}; *(float4*)&outF[base] = o; }
  if (outB){
    outB[base+0] = f2b(o0); outB[base+1] = f2b(o1);
    outB[base+2] = f2b(o2); outB[base+3] = f2b(o3);
  }
}

// ---------------- launch ----------------
extern "C" void kernel_launch(void* const* d_in, const int* in_sizes, int n_in,
                              void* d_out, int out_size, void* d_ws, size_t ws_size,
                              hipStream_t stream){
  const float* x    = (const float*)d_in[0];
  const int*   ei   = (const int*)  d_in[1];
  const float* demb = (const float*)d_in[2];
  const float* spa  = (const float*)d_in[3];
  const float* Wq   = (const float*)d_in[4];
  const float* bq   = (const float*)d_in[5];
  const float* Wk   = (const float*)d_in[6];
  const float* bk   = (const float*)d_in[7];
  const float* Wv   = (const float*)d_in[8];
  const float* bv   = (const float*)d_in[9];
  const float* Wo   = (const float*)d_in[10];
  const float* bo   = (const float*)d_in[11];
  const float* g1   = (const float*)d_in[12];
  const float* b1   = (const float*)d_in[13];
  const float* g2   = (const float*)d_in[14];
  const float* b2   = (const float*)d_in[15];
  const float* Wf1  = (const float*)d_in[16];
  const float* bf1  = (const float*)d_in[17];
  const float* Wf2  = (const float*)d_in[18];
  const float* bf2  = (const float*)d_in[19];

  char* ws = (char*)d_ws;
  size_t off = 0;
  auto take = [&](size_t bytes)->char*{
    char* p = ws + off;
    off = (off + bytes + 255) & ~(size_t)255;
    return p;
  };
  int* deg   = (int*)take(4096 * 4);
  int* rowp  = (int*)take(4097 * 4);
  int* cur   = (int*)take(4096 * 4);
  int* col   = (int*)take(131072 * 4);
  u16* hid   = (u16*)take(2097152);
  u16* Wqt   = (u16*)take(131072);
  u16* Wkt   = (u16*)take(131072);
  u16* Wvt   = (u16*)take(131072);
  u16* Wot   = (u16*)take(131072);
  u16* Wf1t  = (u16*)take(262144);
  u16* Wf2t  = (u16*)take(262144);
  u16* qb    = (u16*)take(2097152);
  u16* kb    = (u16*)take(2097152);
  u16* vt    = (u16*)take(2097152);
  u16* attb  = (u16*)take(2097152);
  char* Bb   = take(5 * 2097152);          // BFS buffers; later aliased
  unsigned char* dist = (unsigned char*)take(16777216); // later aliased
  u64* B[5];
  for (int i = 0; i < 5; i++) B[i] = (u64*)(Bb + (size_t)i * 2097152);
  float* attnout = (float*)Bb;                     // 4 MB (B0,B1) — dead after k_dist
  float* hf      = (float*)(Bb + 4194304);          // 4 MB (B2,B3)
  u16*   hbf     = (u16*)  (Bb + 8388608);          // 2 MB (B4)
  u16*   ff1     = (u16*)  dist;                    // 4 MB — dist dead after k_attn
  float* ff2     = (float*)(dist + 8388608);        // 4 MB
  float* outp    = (float*)d_out;

  hipMemsetAsync(deg, 0, 4096 * 4, stream);
  k_deg  <<<256,  256, 0, stream>>>(ei, deg);
  k_scan <<<1,    256, 0, stream>>>(deg, rowp, cur);
  k_fill <<<256,  256, 0, stream>>>(ei, cur, col);
  k_hidden<<<4096,256, 0, stream>>>(x, demb, deg, hid);
  k_b0   <<<1024, 256, 0, stream>>>(B[0]);
  for (int d = 0; d < 4; d++)
    k_prop<<<1024, 256, 0, stream>>>(B[d], B[d + 1], rowp, col);
  k_dist <<<1024, 256, 0, stream>>>(B[1], B[2], B[3], B[4], dist);

  k_wconv<<<256, 256, 0, stream>>>(Wq,  Wqt,  256, 256);
  k_wconv<<<256, 256, 0, stream>>>(Wk,  Wkt,  256, 256);
  k_wconv<<<256, 256, 0, stream>>>(Wv,  Wvt,  256, 256);
  k_wconv<<<256, 256, 0, stream>>>(Wo,  Wot,  256, 256);
  k_wconv<<<512, 256, 0, stream>>>(Wf1, Wf1t, 256, 512);
  k_wconv<<<512, 256, 0, stream>>>(Wf2, Wf2t, 512, 256);

  k_gemm<<<dim3(64, 4), 256, 0, stream>>>(hid,  Wqt,  bq,  nullptr, qb,  4096, 256, 256, 2);
  k_gemm<<<dim3(64, 4), 256, 0, stream>>>(hid,  Wkt,  bk,  nullptr, kb,  4096, 256, 256, 2);
  k_gemm<<<dim3(64, 4), 256, 0, stream>>>(hid,  Wvt,  bv,  nullptr, vt,  4096, 256, 256, 4);

  k_attn<<<dim3(128, 2), 256, 0, stream>>>(qb, kb, vt, dist, spa, attb);

  k_gemm<<<dim3(64, 4), 256, 0, stream>>>(attb, Wot,  bo,  attnout, nullptr, 4096, 256, 256, 1);
  k_ln  <<<1024, 256, 0, stream>>>(x, attnout, g1, b1, hf, hbf);
  k_gemm<<<dim3(64, 8), 256, 0, stream>>>(hbf,  Wf1t, bf1, nullptr, ff1, 4096, 512, 256, 2 | 8);
  k_gemm<<<dim3(64, 4), 256, 0, stream>>>(ff1,  Wf2t, bf2, ff2,     nullptr, 4096, 256, 512, 1);
  k_ln  <<<1024, 256, 0, stream>>>(hf, ff2, g2, b2, outp, nullptr);
}

// Round 2
// 377.044 us; speedup vs baseline: 1.1589x; 1.1589x over previous
//
#include <hip/hip_runtime.h>
#include <math.h>

#define NN 4096
#define CC 256
#define HH 8
#define DD 32
#define EE 65536

typedef unsigned short u16;
typedef unsigned int u32;
typedef unsigned long long u64;

typedef float f32x4 __attribute__((ext_vector_type(4)));
typedef __bf16 bf16x8 __attribute__((ext_vector_type(8)));

__device__ __forceinline__ u16 f2b(float f){
  u32 u = __float_as_uint(f);
  return (u16)((u + 0x7FFFu + ((u >> 16) & 1u)) >> 16);
}

// ---------------- graph: degree, CSR ----------------
__global__ __launch_bounds__(256) void k_deg(const int* __restrict__ ei, int* __restrict__ deg){
  int e = blockIdx.x * 256 + threadIdx.x;
  if (e < EE){
    atomicAdd(&deg[ei[e]], 1);
    atomicAdd(&deg[ei[EE + e]], 1);
  }
}

__global__ __launch_bounds__(256) void k_scan(const int* __restrict__ deg, int* __restrict__ rowp,
                                              int* __restrict__ cur){
  __shared__ int part[256];
  int t = threadIdx.x;
  int local[16];
  int s = 0;
  #pragma unroll
  for (int i = 0; i < 16; i++){ local[i] = s; s += deg[t*16 + i]; }
  part[t] = s;
  __syncthreads();
  for (int off = 1; off < 256; off <<= 1){
    int v = (t >= off) ? part[t - off] : 0;
    __syncthreads();
    part[t] += v;
    __syncthreads();
  }
  int excl = (t == 0) ? 0 : part[t - 1];
  #pragma unroll
  for (int i = 0; i < 16; i++){ int v = excl + local[i]; rowp[t*16+i] = v; cur[t*16+i] = v; }
  if (t == 255) rowp[4096] = excl + s;
}

__global__ __launch_bounds__(256) void k_fill(const int* __restrict__ ei, int* __restrict__ cur,
                                              int* __restrict__ col){
  int e = blockIdx.x * 256 + threadIdx.x;
  if (e < EE){
    int r = ei[e], c = ei[EE + e];
    col[atomicAdd(&cur[r], 1)] = c;
    col[atomicAdd(&cur[c], 1)] = r;
  }
}

// ---------------- hidden = x + deg_emb[min(deg,33)] (bf16) ----------------
__global__ __launch_bounds__(256) void k_hidden(const float* __restrict__ x, const float* __restrict__ demb,
                                                const int* __restrict__ deg, u16* __restrict__ hb){
  int i = blockIdx.x * 256 + threadIdx.x;
  int n = i >> 8, c = i & 255;
  int d = deg[n]; if (d > 33) d = 33;
  hb[i] = f2b(x[i] + demb[d * CC + c]);
}

// ---------------- bit-parallel BFS ----------------
__global__ __launch_bounds__(256) void k_b0(u64* __restrict__ B0){
  int i = blockIdx.x * 256 + threadIdx.x;
  int j = i >> 6, w = i & 63;
  B0[i] = (w == (j >> 6)) ? (1ull << (j & 63)) : 0ull;
}

__global__ __launch_bounds__(256) void k_prop(const u64* __restrict__ Bp, u64* __restrict__ Bn,
                                              const int* __restrict__ rowp, const int* __restrict__ col){
  int i = blockIdx.x * 256 + threadIdx.x;
  int j = i >> 6, w = i & 63;
  u64 acc = Bp[i];
  int s = rowp[j], e = rowp[j + 1];
  for (int p = s; p < e; p++){
    acc |= Bp[(col[p] << 6) + w];
  }
  Bn[i] = acc;
}

__global__ __launch_bounds__(256) void k_dist(const u64* __restrict__ B1, const u64* __restrict__ B2,
                                              const u64* __restrict__ B3, const u64* __restrict__ B4,
                                              unsigned char* __restrict__ dist){
  int i = blockIdx.x * 256 + threadIdx.x;
  int j = i >> 6, w = i & 63;
  u64 b1 = B1[i], b2 = B2[i], b3 = B3[i], b4 = B4[i];
  u32 ob[16];
  #pragma unroll
  for (int g = 0; g < 16; g++){
    u32 word = 0;
    #pragma unroll
    for (int q = 0; q < 4; q++){
      int bit = g * 4 + q;
      u32 d;
      if ((b1 >> bit) & 1) d = 1;
      else if ((b2 >> bit) & 1) d = 2;
      else if ((b3 >> bit) & 1) d = 3;
      else if ((b4 >> bit) & 1) d = 4;
      else d = 5;
      if ((w << 6) + bit == j) d = 0;
      word |= d << (q * 8);
    }
    ob[g] = word;
  }
  uint4* dp = (uint4*)(dist + ((size_t)j << 12) + (w << 6));
  uint4* ov = (uint4*)ob;
  dp[0] = ov[0]; dp[1] = ov[1]; dp[2] = ov[2]; dp[3] = ov[3];
}

// ---------------- weight convert: fp32 [K][N] -> bf16 transposed [N][K] ----------------
__global__ __launch_bounds__(256) void k_wconv(const float* __restrict__ W, u16* __restrict__ Wt,
                                               int K, int N){
  int i = blockIdx.x * 256 + threadIdx.x;
  if (i < K * N){
    int n = i / K, k = i - n * K;
    Wt[i] = f2b(W[k * N + n]);
  }
}

__global__ __launch_bounds__(256) void k_bcat(const float* __restrict__ a, const float* __restrict__ b,
                                              const float* __restrict__ c, float* __restrict__ o){
  int i = blockIdx.x * 256 + threadIdx.x;
  if (i < 768){
    float v = (i < 256) ? a[i] : (i < 512) ? b[i - 256] : c[i - 512];
    o[i] = v;
  }
}

// ---------------- bf16 MFMA GEMM, 32x64 tile, K-step 64 ----------------
// mode: 1 = f32 out [M][N]; 2 = bf16 out [M][OS]; 8 = exact GELU.
// outT != null: columns >= 512 go transposed to outT[(gn-512)*M + gm] (QKV fused V path).
__global__ __launch_bounds__(256) void k_gemm32(const u16* __restrict__ A, const u16* __restrict__ Wt,
                                                const float* __restrict__ bias,
                                                float* __restrict__ outF, u16* __restrict__ outB,
                                                u16* __restrict__ outT,
                                                int M, int N, int K, int OS, int mode){
  __shared__ __align__(16) u16 As[32][72];
  __shared__ __align__(16) u16 Bs[64][72];
  int t = threadIdx.x;
  int lane = t & 63;
  int wv = t >> 6;
  int m0 = blockIdx.x * 32, n0 = blockIdx.y * 64;
  int ar = t >> 3, ak = (t & 7) * 8;      // As staging 32x64
  int br = t >> 2, bk = (t & 3) * 16;     // Bs staging 64x64 (two 8-chunks)
  int row16 = lane & 15, kq = (lane >> 4) * 8, rg = (lane >> 4) * 4;
  f32x4 acc0 = {0.f,0.f,0.f,0.f}, acc1 = {0.f,0.f,0.f,0.f};
  for (int k0 = 0; k0 < K; k0 += 64){
    __syncthreads();
    *(bf16x8*)&As[ar][ak]   = *(const bf16x8*)&A [(size_t)(m0 + ar) * K + k0 + ak];
    *(bf16x8*)&Bs[br][bk]   = *(const bf16x8*)&Wt[(size_t)(n0 + br) * K + k0 + bk];
    *(bf16x8*)&Bs[br][bk+8] = *(const bf16x8*)&Wt[(size_t)(n0 + br) * K + k0 + bk + 8];
    __syncthreads();
    #pragma unroll
    for (int ks = 0; ks < 2; ks++){
      bf16x8 a0 = *(const bf16x8*)&As[     row16][ks*32 + kq];
      bf16x8 a1 = *(const bf16x8*)&As[16 + row16][ks*32 + kq];
      bf16x8 b  = *(const bf16x8*)&Bs[wv*16 + row16][ks*32 + kq];
      acc0 = __builtin_amdgcn_mfma_f32_16x16x32_bf16(a0, b, acc0, 0, 0, 0);
      acc1 = __builtin_amdgcn_mfma_f32_16x16x32_bf16(a1, b, acc1, 0, 0, 0);
    }
  }
  int gn = n0 + wv*16 + row16;
  float bv = bias[gn];
  #pragma unroll
  for (int fm = 0; fm < 2; fm++){
    f32x4 aa = fm ? acc1 : acc0;
    #pragma unroll
    for (int r = 0; r < 4; r++){
      int gm = m0 + fm*16 + rg + r;
      float v = aa[r] + bv;
      if (mode & 8) v = 0.5f * v * (1.0f + erff(v * 0.70710678118654752f));
      if (outT && gn >= 512)      outT[(size_t)(gn - 512) * M + gm] = f2b(v);
      else if (mode & 1)          outF[(size_t)gm * N + gn] = v;
      else                        outB[(size_t)gm * OS + gn] = f2b(v);
    }
  }
}

// ---------------- flash attention, split-K over 4 chunks of 1024 keys ----------------
// WG: 32 queries x 4 heads (1 head/wave). Writes unnormalized partials + (m,l).
__global__ __launch_bounds__(256) void k_attn(const u16* __restrict__ qg, const u16* __restrict__ kg,
                                              int CS, const u16* __restrict__ vtg,
                                              const unsigned char* __restrict__ dist,
                                              const float* __restrict__ spa,
                                              float* __restrict__ pacc, float* __restrict__ pml){
  __shared__ __align__(16) u16 P[4][32][72];
  __shared__ __align__(16) unsigned char dls[64][40];  // [key in tile][query row] via symmetry
  __shared__ float spas[48];
  int t = threadIdx.x;
  int lane = t & 63;
  int wv = t >> 6;
  int h = blockIdx.y * 4 + wv;
  int q0 = blockIdx.x * 32;
  int ck = blockIdx.z;
  int kbase = ck * 1024;
  if (t < 48) spas[t] = spa[t];
  int row16 = lane & 15;
  int kq = (lane >> 4) * 8;
  int rg = (lane >> 4) * 4;
  bf16x8 qf0 = *(const bf16x8*)&qg[(size_t)(q0 +      row16) * CS + h * DD + kq];
  bf16x8 qf1 = *(const bf16x8*)&qg[(size_t)(q0 + 16 + row16) * CS + h * DD + kq];
  f32x4 zero = {0.f, 0.f, 0.f, 0.f};
  f32x4 acc[2][2] = {{zero, zero}, {zero, zero}};
  float ms[2][4], ls[2][4];
  #pragma unroll
  for (int a = 0; a < 2; a++)
    #pragma unroll
    for (int r = 0; r < 4; r++){ ms[a][r] = -INFINITY; ls[a][r] = 0.f; }
  const float scale = 0.17677669529663687f; // 1/sqrt(32)
  int drow = t >> 2, dcol = (t & 3) * 8;    // stage dist[k][q] (symmetric): 64 keys x 32 queries

  for (int kt = kbase; kt < kbase + 1024; kt += 64){
    __syncthreads();
    *(uint2*)&dls[drow][dcol] = *(const uint2*)&dist[(size_t)(kt + drow) * NN + q0 + dcol];
    __syncthreads();
    // QK^T
    f32x4 sc[2][4];
    #pragma unroll
    for (int fn = 0; fn < 4; fn++){
      bf16x8 kf = *(const bf16x8*)&kg[(size_t)(kt + fn*16 + row16) * CS + h * DD + kq];
      sc[0][fn] = __builtin_amdgcn_mfma_f32_16x16x32_bf16(qf0, kf, zero, 0, 0, 0);
      sc[1][fn] = __builtin_amdgcn_mfma_f32_16x16x32_bf16(qf1, kf, zero, 0, 0, 0);
    }
    // scale + spatial bias + row tile-max
    float tmax[2][4];
    #pragma unroll
    for (int a = 0; a < 2; a++)
      #pragma unroll
      for (int r = 0; r < 4; r++) tmax[a][r] = -INFINITY;
    #pragma unroll
    for (int fm = 0; fm < 2; fm++)
      #pragma unroll
      for (int fn = 0; fn < 4; fn++){
        u32 dw = *(const u32*)&dls[fn*16 + row16][fm*16 + rg];
        #pragma unroll
        for (int r = 0; r < 4; r++){
          int b = (dw >> (8*r)) & 255;
          float v = sc[fm][fn][r] * scale + spas[b * 8 + h];
          sc[fm][fn][r] = v;
          tmax[fm][r] = fmaxf(tmax[fm][r], v);
        }
      }
    #pragma unroll
    for (int m = 1; m < 16; m <<= 1)
      #pragma unroll
      for (int fm = 0; fm < 2; fm++)
        #pragma unroll
        for (int r = 0; r < 4; r++)
          tmax[fm][r] = fmaxf(tmax[fm][r], __shfl_xor(tmax[fm][r], m, 64));
    float scl[2][4], rsum[2][4];
    #pragma unroll
    for (int fm = 0; fm < 2; fm++)
      #pragma unroll
      for (int r = 0; r < 4; r++){
        float nm = fmaxf(ms[fm][r], tmax[fm][r]);
        scl[fm][r] = __expf(ms[fm][r] - nm);
        ms[fm][r] = nm;
        rsum[fm][r] = 0.f;
      }
    #pragma unroll
    for (int fm = 0; fm < 2; fm++)
      #pragma unroll
      for (int fn = 0; fn < 4; fn++)
        #pragma unroll
        for (int r = 0; r < 4; r++){
          float p = __expf(sc[fm][fn][r] - ms[fm][r]);
          rsum[fm][r] += p;
          P[wv][fm*16 + rg + r][fn*16 + row16] = f2b(p);
        }
    #pragma unroll
    for (int m = 1; m < 16; m <<= 1)
      #pragma unroll
      for (int fm = 0; fm < 2; fm++)
        #pragma unroll
        for (int r = 0; r < 4; r++)
          rsum[fm][r] += __shfl_xor(rsum[fm][r], m, 64);
    #pragma unroll
    for (int fm = 0; fm < 2; fm++)
      #pragma unroll
      for (int r = 0; r < 4; r++)
        ls[fm][r] = ls[fm][r] * scl[fm][r] + rsum[fm][r];
    #pragma unroll
    for (int fm = 0; fm < 2; fm++)
      #pragma unroll
      for (int fd = 0; fd < 2; fd++)
        #pragma unroll
        for (int r = 0; r < 4; r++)
          acc[fm][fd][r] *= scl[fm][r];
    // PV
    #pragma unroll
    for (int ks = 0; ks < 2; ks++){
      bf16x8 pa0 = *(const bf16x8*)&P[wv][     row16][ks*32 + kq];
      bf16x8 pa1 = *(const bf16x8*)&P[wv][16 + row16][ks*32 + kq];
      #pragma unroll
      for (int fd = 0; fd < 2; fd++){
        bf16x8 vf = *(const bf16x8*)&vtg[(size_t)(h*DD + fd*16 + row16) * NN + kt + ks*32 + kq];
        acc[0][fd] = __builtin_amdgcn_mfma_f32_16x16x32_bf16(pa0, vf, acc[0][fd], 0, 0, 0);
        acc[1][fd] = __builtin_amdgcn_mfma_f32_16x16x32_bf16(pa1, vf, acc[1][fd], 0, 0, 0);
      }
    }
  }
  // write partials
  size_t base = ((size_t)ck * 8 + h) * 4096 + q0;
  #pragma unroll
  for (int fm = 0; fm < 2; fm++)
    #pragma unroll
    for (int fd = 0; fd < 2; fd++)
      #pragma unroll
      for (int r = 0; r < 4; r++)
        pacc[(base + fm*16 + rg + r) * 32 + fd*16 + row16] = acc[fm][fd][r];
  if (row16 == 0){
    #pragma unroll
    for (int fm = 0; fm < 2; fm++)
      #pragma unroll
      for (int r = 0; r < 4; r++){
        pml[(base + fm*16 + rg + r) * 2 + 0] = ms[fm][r];
        pml[(base + fm*16 + rg + r) * 2 + 1] = ls[fm][r];
      }
  }
}

// ---------------- split-K merge ----------------
__global__ __launch_bounds__(256) void k_merge(const float* __restrict__ pacc,
                                               const float* __restrict__ pml,
                                               u16* __restrict__ attb){
  int row = blockIdx.x;
  int t = threadIdx.x;
  int h = t >> 5, col = t & 31;
  float mc[4], lc[4];
  float m = -INFINITY;
  #pragma unroll
  for (int c = 0; c < 4; c++){
    size_t base = ((size_t)c * 8 + h) * 4096 + row;
    mc[c] = pml[base * 2 + 0];
    lc[c] = pml[base * 2 + 1];
    m = fmaxf(m, mc[c]);
  }
  float L = 0.f, o = 0.f;
  #pragma unroll
  for (int c = 0; c < 4; c++){
    size_t base = ((size_t)c * 8 + h) * 4096 + row;
    float w = __expf(mc[c] - m);
    L += lc[c] * w;
    o += pacc[base * 32 + col] * w;
  }
  attb[(size_t)row * 256 + h * 32 + col] = f2b(o / L);
}

// ---------------- residual + LayerNorm (wave per row) ----------------
__global__ __launch_bounds__(256) void k_ln(const float* __restrict__ ina, const float* __restrict__ inb,
                                            const float* __restrict__ g, const float* __restrict__ b,
                                            float* __restrict__ outF, u16* __restrict__ outB){
  int t = threadIdx.x;
  int wv = t >> 6, lane = t & 63;
  int row = blockIdx.x * 4 + wv;
  size_t base = (size_t)row * CC + lane * 4;
  float4 xa = *(const float4*)&ina[base];
  float4 xb = *(const float4*)&inb[base];
  float v0 = xa.x + xb.x, v1 = xa.y + xb.y, v2 = xa.z + xb.z, v3 = xa.w + xb.w;
  float s  = v0 + v1 + v2 + v3;
  float s2 = v0*v0 + v1*v1 + v2*v2 + v3*v3;
  #pragma unroll
  for (int m = 1; m < 64; m <<= 1){
    s  += __shfl_xor(s,  m, 64);
    s2 += __shfl_xor(s2, m, 64);
  }
  float mu  = s * (1.0f / 256.0f);
  float var = s2 * (1.0f / 256.0f) - mu * mu;
  float rs  = rsqrtf(var + 1e-5f);
  float4 gv = *(const float4*)&g[lane * 4];
  float4 bv = *(const float4*)&b[lane * 4];
  float o0 = (v0 - mu) * rs * gv.x + bv.x;
  float o1 = (v1 - mu) * rs * gv.y + bv.y;
  float o2 = (v2 - mu) * rs * gv.z + bv.z;
  float o3 = (v3 - mu) * rs * gv.w + bv.w;
  if (outF){ float4 o = {o0, o1, o2, o3}; *(float4*)&outF[base] = o; }
  if (outB){
    outB[base+0] = f2b(o0); outB[base+1] = f2b(o1);
    outB[base+2] = f2b(o2); outB[base+3] = f2b(o3);
  }
}

// ---------------- launch ----------------
extern "C" void kernel_launch(void* const* d_in, const int* in_sizes, int n_in,
                              void* d_out, int out_size, void* d_ws, size_t ws_size,
                              hipStream_t stream){
  const float* x    = (const float*)d_in[0];
  const int*   ei   = (const int*)  d_in[1];
  const float* demb = (const float*)d_in[2];
  const float* spa  = (const float*)d_in[3];
  const float* Wq   = (const float*)d_in[4];
  const float* bq   = (const float*)d_in[5];
  const float* Wk   = (const float*)d_in[6];
  const float* bk   = (const float*)d_in[7];
  const float* Wv   = (const float*)d_in[8];
  const float* bv   = (const float*)d_in[9];
  const float* Wo   = (const float*)d_in[10];
  const float* bo   = (const float*)d_in[11];
  const float* g1   = (const float*)d_in[12];
  const float* b1   = (const float*)d_in[13];
  const float* g2   = (const float*)d_in[14];
  const float* b2   = (const float*)d_in[15];
  const float* Wf1  = (const float*)d_in[16];
  const float* bf1  = (const float*)d_in[17];
  const float* Wf2  = (const float*)d_in[18];
  const float* bf2  = (const float*)d_in[19];

  char* ws = (char*)d_ws;
  size_t off = 0;
  auto take = [&](size_t bytes)->char*{
    char* p = ws + off;
    off = (off + bytes + 255) & ~(size_t)255;
    return p;
  };
  int* deg    = (int*)take(4096 * 4);
  int* rowp   = (int*)take(4097 * 4);
  int* cur    = (int*)take(4096 * 4);
  int* col    = (int*)take(131072 * 4);
  u16* hid    = (u16*)take(2097152);
  u16* Wqkvt  = (u16*)take(768 * 256 * 2);
  u16* Wot    = (u16*)take(131072);
  u16* Wf1t   = (u16*)take(262144);
  u16* Wf2t   = (u16*)take(262144);
  float* bcat = (float*)take(768 * 4);
  u16* qkv    = (u16*)take(4194304);        // [4096][512] Q|K bf16
  u16* vt     = (u16*)take(2097152);        // [256][4096] V transposed
  u16* attb   = (u16*)take(2097152);
  char* SC    = take(17 * 1048576 + 1048576);   // BFS / attn partials / post-attn scratch
  unsigned char* dist = (unsigned char*)take(16777216);  // ff1/ff2 alias later
  u64* B[5];
  for (int i = 0; i < 5; i++) B[i] = (u64*)(SC + (size_t)i * 2097152);
  float* pacc    = (float*)SC;                       // 16 MB (after k_dist, B dead)
  float* pml     = (float*)(SC + 16777216);          // 1 MB
  float* attnout = (float*)SC;                       // 4 MB (after merge, pacc dead)
  float* hf      = (float*)(SC + 4194304);           // 4 MB
  u16*   hbf     = (u16*)  (SC + 8388608);           // 2 MB
  u16*   ff1     = (u16*)  dist;                     // 4 MB (dist dead after attn)
  float* ff2     = (float*)(dist + 8388608);         // 4 MB
  float* outp    = (float*)d_out;

  hipMemsetAsync(deg, 0, 4096 * 4, stream);
  k_deg   <<<256,  256, 0, stream>>>(ei, deg);
  k_scan  <<<1,    256, 0, stream>>>(deg, rowp, cur);
  k_fill  <<<256,  256, 0, stream>>>(ei, cur, col);
  k_hidden<<<4096, 256, 0, stream>>>(x, demb, deg, hid);
  k_b0    <<<1024, 256, 0, stream>>>(B[0]);
  for (int d = 0; d < 4; d++)
    k_prop<<<1024, 256, 0, stream>>>(B[d], B[d + 1], rowp, col);
  k_dist  <<<1024, 256, 0, stream>>>(B[1], B[2], B[3], B[4], dist);

  k_wconv<<<256, 256, 0, stream>>>(Wq,  Wqkvt,             256, 256);
  k_wconv<<<256, 256, 0, stream>>>(Wk,  Wqkvt + 256 * 256, 256, 256);
  k_wconv<<<256, 256, 0, stream>>>(Wv,  Wqkvt + 512 * 256, 256, 256);
  k_wconv<<<256, 256, 0, stream>>>(Wo,  Wot,  256, 256);
  k_wconv<<<512, 256, 0, stream>>>(Wf1, Wf1t, 256, 512);
  k_wconv<<<512, 256, 0, stream>>>(Wf2, Wf2t, 512, 256);
  k_bcat <<<3,   256, 0, stream>>>(bq, bk, bv, bcat);

  // fused QKV: N=768; cols [0,512) -> qkv row-major (stride 512), cols [512,768) -> vt transposed
  k_gemm32<<<dim3(128, 12), 256, 0, stream>>>(hid, Wqkvt, bcat, nullptr, qkv, vt,
                                              4096, 768, 256, 512, 2);

  k_attn <<<dim3(128, 2, 4), 256, 0, stream>>>(qkv, qkv + 256, 512, vt, dist, spa, pacc, pml);
  k_merge<<<4096, 256, 0, stream>>>(pacc, pml, attb);

  k_gemm32<<<dim3(128, 4), 256, 0, stream>>>(attb, Wot, bo, attnout, nullptr, nullptr,
                                             4096, 256, 256, 256, 1);
  k_ln   <<<1024, 256, 0, stream>>>(x, attnout, g1, b1, hf, hbf);
  k_gemm32<<<dim3(128, 8), 256, 0, stream>>>(hbf, Wf1t, bf1, nullptr, ff1, nullptr,
                                             4096, 512, 256, 512, 2 | 8);
  k_gemm32<<<dim3(128, 4), 256, 0, stream>>>(ff1, Wf2t, bf2, ff2, nullptr, nullptr,
                                             4096, 256, 512, 256, 1);
  k_ln   <<<1024, 256, 0, stream>>>(hf, ff2, g2, b2, outp, nullptr);
}

// Round 3
// 351.760 us; speedup vs baseline: 1.2422x; 1.0719x over previous
//
#include <hip/hip_runtime.h>
#include <math.h>

#define NN 4096
#define CC 256
#define HH 8
#define DD 32
#define EE 65536

typedef unsigned short u16;
typedef unsigned int u32;
typedef unsigned long long u64;
typedef unsigned char u8;

typedef float f32x4 __attribute__((ext_vector_type(4)));
typedef __bf16 bf16x8 __attribute__((ext_vector_type(8)));

__device__ __forceinline__ u16 f2b(float f){
  u32 u = __float_as_uint(f);
  return (u16)((u + 0x7FFFu + ((u >> 16) & 1u)) >> 16);
}
__device__ __forceinline__ u32 pk2(float a, float b){
  u32 r; asm("v_cvt_pk_bf16_f32 %0,%1,%2" : "=v"(r) : "v"(a), "v"(b)); return r;
}

// ---------------- graph: degree, CSR ----------------
__global__ __launch_bounds__(256) void k_deg(const int* __restrict__ ei, int* __restrict__ deg){
  int e = blockIdx.x * 256 + threadIdx.x;
  if (e < EE){
    atomicAdd(&deg[ei[e]], 1);
    atomicAdd(&deg[ei[EE + e]], 1);
  }
}

__global__ __launch_bounds__(256) void k_scan(const int* __restrict__ deg, int* __restrict__ rowp,
                                              int* __restrict__ cur){
  __shared__ int part[256];
  int t = threadIdx.x;
  int local[16];
  int s = 0;
  #pragma unroll
  for (int i = 0; i < 16; i++){ local[i] = s; s += deg[t*16 + i]; }
  part[t] = s;
  __syncthreads();
  for (int off = 1; off < 256; off <<= 1){
    int v = (t >= off) ? part[t - off] : 0;
    __syncthreads();
    part[t] += v;
    __syncthreads();
  }
  int excl = (t == 0) ? 0 : part[t - 1];
  #pragma unroll
  for (int i = 0; i < 16; i++){ int v = excl + local[i]; rowp[t*16+i] = v; cur[t*16+i] = v; }
  if (t == 255) rowp[4096] = excl + s;
}

__global__ __launch_bounds__(256) void k_fill(const int* __restrict__ ei, int* __restrict__ cur,
                                              int* __restrict__ col){
  int e = blockIdx.x * 256 + threadIdx.x;
  if (e < EE){
    int r = ei[e], c = ei[EE + e];
    col[atomicAdd(&cur[r], 1)] = c;
    col[atomicAdd(&cur[c], 1)] = r;
  }
}

// ---------------- hidden = x + deg_emb[min(deg,33)] (bf16) ----------------
__global__ __launch_bounds__(256) void k_hidden(const float* __restrict__ x, const float* __restrict__ demb,
                                                const int* __restrict__ deg, u16* __restrict__ hb){
  int i = blockIdx.x * 256 + threadIdx.x;
  int n = i >> 8, c = i & 255;
  int d = deg[n]; if (d > 33) d = 33;
  hb[i] = f2b(x[i] + demb[d * CC + c]);
}

// ---------------- bit-parallel BFS ----------------
__global__ __launch_bounds__(256) void k_b0(u64* __restrict__ B0){
  int i = blockIdx.x * 256 + threadIdx.x;
  int j = i >> 6, w = i & 63;
  B0[i] = (w == (j >> 6)) ? (1ull << (j & 63)) : 0ull;
}

__global__ __launch_bounds__(256) void k_prop(const u64* __restrict__ Bp, u64* __restrict__ Bn,
                                              const int* __restrict__ rowp, const int* __restrict__ col){
  int i = blockIdx.x * 256 + threadIdx.x;
  int j = i >> 6, w = i & 63;
  u64 acc = Bp[i];
  int s = rowp[j], e = rowp[j + 1];
  for (int p = s; p < e; p++){
    acc |= Bp[(col[p] << 6) + w];
  }
  Bn[i] = acc;
}

__global__ __launch_bounds__(256) void k_dist(const u64* __restrict__ B1, const u64* __restrict__ B2,
                                              const u64* __restrict__ B3, const u64* __restrict__ B4,
                                              u8* __restrict__ dist){
  int i = blockIdx.x * 256 + threadIdx.x;
  int j = i >> 6, w = i & 63;
  u64 b1 = B1[i], b2 = B2[i], b3 = B3[i], b4 = B4[i];
  u32 ob[16];
  #pragma unroll
  for (int g = 0; g < 16; g++){
    u32 word = 0;
    #pragma unroll
    for (int q = 0; q < 4; q++){
      int bit = g * 4 + q;
      u32 d;
      if ((b1 >> bit) & 1) d = 1;
      else if ((b2 >> bit) & 1) d = 2;
      else if ((b3 >> bit) & 1) d = 3;
      else if ((b4 >> bit) & 1) d = 4;
      else d = 5;
      if ((w << 6) + bit == j) d = 0;
      word |= d << (q * 8);
    }
    ob[g] = word;
  }
  uint4* dp = (uint4*)(dist + ((size_t)j << 12) + (w << 6));
  uint4* ov = (uint4*)ob;
  dp[0] = ov[0]; dp[1] = ov[1]; dp[2] = ov[2]; dp[3] = ov[3];
}

// ---------------- weight transpose+convert: fp32 [K][N] -> bf16 [N][K], coalesced ----------------
// z selects weight; 64x64 tiles via LDS.
__global__ __launch_bounds__(256) void k_tconv(const float* __restrict__ W0, const float* __restrict__ W1,
                                               const float* __restrict__ W2, const float* __restrict__ W3,
                                               const float* __restrict__ W4, const float* __restrict__ W5,
                                               u16* __restrict__ T0, u16* __restrict__ T1,
                                               u16* __restrict__ T2, u16* __restrict__ T3,
                                               u16* __restrict__ T4, u16* __restrict__ T5){
  __shared__ float Ts[64][65];
  int z = blockIdx.z;
  const float* W; u16* T; int K, N;
  switch (z){
    case 0: W = W0; T = T0; K = 256; N = 256; break;
    case 1: W = W1; T = T1; K = 256; N = 256; break;
    case 2: W = W2; T = T2; K = 256; N = 256; break;
    case 3: W = W3; T = T3; K = 256; N = 256; break;
    case 4: W = W4; T = T4; K = 256; N = 512; break;
    default: W = W5; T = T5; K = 512; N = 256; break;
  }
  int n0 = blockIdx.x * 64, k0 = blockIdx.y * 64;
  if (n0 >= N || k0 >= K) return;
  int t = threadIdx.x;
  int r = t >> 4, c4 = (t & 15) * 4;
  #pragma unroll
  for (int it = 0; it < 4; it++){
    float4 v = *(const float4*)&W[(size_t)(k0 + it*16 + r) * N + n0 + c4];
    Ts[it*16 + r][c4+0] = v.x; Ts[it*16 + r][c4+1] = v.y;
    Ts[it*16 + r][c4+2] = v.z; Ts[it*16 + r][c4+3] = v.w;
  }
  __syncthreads();
  #pragma unroll
  for (int it = 0; it < 4; it++){
    int n = it*16 + r;
    uint2 o;
    o.x = pk2(Ts[c4+0][n], Ts[c4+1][n]);
    o.y = pk2(Ts[c4+2][n], Ts[c4+3][n]);
    *(uint2*)&T[(size_t)(n0 + n) * K + k0 + c4] = o;
  }
}

__global__ __launch_bounds__(256) void k_bcat(const float* __restrict__ a, const float* __restrict__ b,
                                              const float* __restrict__ c, float* __restrict__ o){
  int i = blockIdx.x * 256 + threadIdx.x;
  if (i < 768){
    float v = (i < 256) ? a[i] : (i < 512) ? b[i - 256] : c[i - 512];
    o[i] = v;
  }
}

// ---------------- bf16 MFMA GEMM, 32x64 tile, K-step 64 ----------------
__global__ __launch_bounds__(256) void k_gemm32(const u16* __restrict__ A, const u16* __restrict__ Wt,
                                                const float* __restrict__ bias,
                                                float* __restrict__ outF, u16* __restrict__ outB,
                                                u16* __restrict__ outT,
                                                int M, int N, int K, int OS, int mode){
  __shared__ __align__(16) u16 As[32][72];
  __shared__ __align__(16) u16 Bs[64][72];
  int t = threadIdx.x;
  int lane = t & 63;
  int wv = t >> 6;
  int m0 = blockIdx.x * 32, n0 = blockIdx.y * 64;
  int ar = t >> 3, ak = (t & 7) * 8;
  int br = t >> 2, bk = (t & 3) * 16;
  int row16 = lane & 15, kq = (lane >> 4) * 8, rg = (lane >> 4) * 4;
  f32x4 acc0 = {0.f,0.f,0.f,0.f}, acc1 = {0.f,0.f,0.f,0.f};
  for (int k0 = 0; k0 < K; k0 += 64){
    __syncthreads();
    *(bf16x8*)&As[ar][ak]   = *(const bf16x8*)&A [(size_t)(m0 + ar) * K + k0 + ak];
    *(bf16x8*)&Bs[br][bk]   = *(const bf16x8*)&Wt[(size_t)(n0 + br) * K + k0 + bk];
    *(bf16x8*)&Bs[br][bk+8] = *(const bf16x8*)&Wt[(size_t)(n0 + br) * K + k0 + bk + 8];
    __syncthreads();
    #pragma unroll
    for (int ks = 0; ks < 2; ks++){
      bf16x8 a0 = *(const bf16x8*)&As[     row16][ks*32 + kq];
      bf16x8 a1 = *(const bf16x8*)&As[16 + row16][ks*32 + kq];
      bf16x8 b  = *(const bf16x8*)&Bs[wv*16 + row16][ks*32 + kq];
      acc0 = __builtin_amdgcn_mfma_f32_16x16x32_bf16(a0, b, acc0, 0, 0, 0);
      acc1 = __builtin_amdgcn_mfma_f32_16x16x32_bf16(a1, b, acc1, 0, 0, 0);
    }
  }
  int gn = n0 + wv*16 + row16;
  float bv = bias[gn];
  #pragma unroll
  for (int fm = 0; fm < 2; fm++){
    f32x4 aa = fm ? acc1 : acc0;
    #pragma unroll
    for (int r = 0; r < 4; r++){
      int gm = m0 + fm*16 + rg + r;
      float v = aa[r] + bv;
      if (mode & 8) v = 0.5f * v * (1.0f + erff(v * 0.70710678118654752f));
      if (outT && gn >= 512)      outT[(size_t)(gn - 512) * M + gm] = f2b(v);
      else if (mode & 1)          outF[(size_t)gm * N + gn] = v;
      else                        outB[(size_t)gm * OS + gn] = f2b(v);
    }
  }
}

// ---------------- flash attention: swapped QK^T, barrier-free K-loop, split-K z=4 ----------------
__global__ __launch_bounds__(256) void k_attn(const u16* __restrict__ qg, const u16* __restrict__ kg,
                                              int CS, const u16* __restrict__ vtg,
                                              const u8* __restrict__ dist,
                                              const float* __restrict__ spa,
                                              float* __restrict__ pacc, float* __restrict__ pml){
  __shared__ __align__(16) u16 P[4][32][72];     // per-wave [q][k]
  __shared__ __align__(16) u8 dls[4][32][72];    // per-wave [q][k]
  __shared__ float spas[48];
  int t = threadIdx.x;
  int lane = t & 63;
  int wv = t >> 6;
  int h = blockIdx.y * 4 + wv;
  int q0 = blockIdx.x * 32;
  int ck = blockIdx.z;
  int kbase = ck * 1024;
  if (t < 48) spas[t] = spa[t] * 1.4426950408889634f;   // pre-mul log2(e)
  __syncthreads();                                      // only barrier in kernel
  int row16 = lane & 15;
  int kq = (lane >> 4) * 8;
  int rg = (lane >> 4) * 4;
  bf16x8 qf0 = *(const bf16x8*)&qg[(size_t)(q0 +      row16) * CS + h * DD + kq];
  bf16x8 qf1 = *(const bf16x8*)&qg[(size_t)(q0 + 16 + row16) * CS + h * DD + kq];
  f32x4 zero = {0.f, 0.f, 0.f, 0.f};
  f32x4 acc[2][2] = {{zero, zero}, {zero, zero}};
  float ms[2] = {-INFINITY, -INFINITY};
  float ls[2] = {0.f, 0.f};
  const float scale2 = 0.25506600600499404f;  // (1/sqrt(32)) * log2(e)
  int srow = lane >> 3, scol = (lane & 7) * 8;

  for (int kt = kbase; kt < kbase + 1024; kt += 64){
    // stage dist tile [32 q][64 k], wave-private (no barriers)
    #pragma unroll
    for (int it = 0; it < 4; it++){
      int rr = it*8 + srow;
      *(uint2*)&dls[wv][rr][scol] = *(const uint2*)&dist[(size_t)(q0 + rr) * NN + kt + scol];
    }
    // swapped QK^T: sc[fm][fn][r] = S[k = fn*16+rg+r][q = q0+fm*16+row16]
    f32x4 sc[2][4];
    #pragma unroll
    for (int fn = 0; fn < 4; fn++){
      bf16x8 kf = *(const bf16x8*)&kg[(size_t)(kt + fn*16 + row16) * CS + h * DD + kq];
      sc[0][fn] = __builtin_amdgcn_mfma_f32_16x16x32_bf16(kf, qf0, zero, 0, 0, 0);
      sc[1][fn] = __builtin_amdgcn_mfma_f32_16x16x32_bf16(kf, qf1, zero, 0, 0, 0);
    }
    float sclr[2];
    #pragma unroll
    for (int fm = 0; fm < 2; fm++){
      int qrow = fm*16 + row16;
      u32 dw[4];
      #pragma unroll
      for (int fn = 0; fn < 4; fn++) dw[fn] = *(const u32*)&dls[wv][qrow][fn*16 + rg];
      float tm = -INFINITY;
      #pragma unroll
      for (int fn = 0; fn < 4; fn++)
        #pragma unroll
        for (int r = 0; r < 4; r++){
          int b = (dw[fn] >> (8*r)) & 255;
          float v = sc[fm][fn][r] * scale2 + spas[b * 8 + h];
          sc[fm][fn][r] = v;
          tm = fmaxf(tm, v);
        }
      tm = fmaxf(tm, __shfl_xor(tm, 16, 64));
      tm = fmaxf(tm, __shfl_xor(tm, 32, 64));
      float nm = fmaxf(ms[fm], tm);
      sclr[fm] = exp2f(ms[fm] - nm);
      ms[fm] = nm;
      float rs = 0.f;
      #pragma unroll
      for (int fn = 0; fn < 4; fn++){
        float p0 = exp2f(sc[fm][fn][0] - nm);
        float p1 = exp2f(sc[fm][fn][1] - nm);
        float p2 = exp2f(sc[fm][fn][2] - nm);
        float p3 = exp2f(sc[fm][fn][3] - nm);
        rs += (p0 + p1) + (p2 + p3);
        uint2 pw = { pk2(p0, p1), pk2(p2, p3) };
        *(uint2*)&P[wv][qrow][fn*16 + rg] = pw;
      }
      rs += __shfl_xor(rs, 16, 64);
      rs += __shfl_xor(rs, 32, 64);
      ls[fm] = ls[fm] * sclr[fm] + rs;
    }
    // redistribute rescale factor to acc layout (q = fm*16 + rg + r)
    #pragma unroll
    for (int fm = 0; fm < 2; fm++)
      #pragma unroll
      for (int r = 0; r < 4; r++){
        float sp = __shfl(sclr[fm], (lane & 48) | (rg + r), 64);
        acc[fm][0][r] *= sp;
        acc[fm][1][r] *= sp;
      }
    // PV
    #pragma unroll
    for (int ks = 0; ks < 2; ks++){
      bf16x8 pa0 = *(const bf16x8*)&P[wv][     row16][ks*32 + kq];
      bf16x8 pa1 = *(const bf16x8*)&P[wv][16 + row16][ks*32 + kq];
      #pragma unroll
      for (int fd = 0; fd < 2; fd++){
        bf16x8 vf = *(const bf16x8*)&vtg[(size_t)(h*DD + fd*16 + row16) * NN + kt + ks*32 + kq];
        acc[0][fd] = __builtin_amdgcn_mfma_f32_16x16x32_bf16(pa0, vf, acc[0][fd], 0, 0, 0);
        acc[1][fd] = __builtin_amdgcn_mfma_f32_16x16x32_bf16(pa1, vf, acc[1][fd], 0, 0, 0);
      }
    }
  }
  // write partials (acc layout)
  size_t base = ((size_t)ck * 8 + h) * 4096 + q0;
  #pragma unroll
  for (int fm = 0; fm < 2; fm++)
    #pragma unroll
    for (int fd = 0; fd < 2; fd++)
      #pragma unroll
      for (int r = 0; r < 4; r++)
        pacc[(base + fm*16 + rg + r) * 32 + fd*16 + row16] = acc[fm][fd][r];
  // write m,l (row16 layout), ms in log2 units
  if ((lane >> 4) == 0){
    #pragma unroll
    for (int fm = 0; fm < 2; fm++){
      pml[(base + fm*16 + row16) * 2 + 0] = ms[fm];
      pml[(base + fm*16 + row16) * 2 + 1] = ls[fm];
    }
  }
}

// ---------------- split-K merge (log2-domain max) ----------------
__global__ __launch_bounds__(256) void k_merge(const float* __restrict__ pacc,
                                               const float* __restrict__ pml,
                                               u16* __restrict__ attb){
  int row = blockIdx.x;
  int t = threadIdx.x;
  int h = t >> 5, col = t & 31;
  float mc[4], lc[4];
  float m = -INFINITY;
  #pragma unroll
  for (int c = 0; c < 4; c++){
    size_t base = ((size_t)c * 8 + h) * 4096 + row;
    mc[c] = pml[base * 2 + 0];
    lc[c] = pml[base * 2 + 1];
    m = fmaxf(m, mc[c]);
  }
  float L = 0.f, o = 0.f;
  #pragma unroll
  for (int c = 0; c < 4; c++){
    size_t base = ((size_t)c * 8 + h) * 4096 + row;
    float w = exp2f(mc[c] - m);
    L += lc[c] * w;
    o += pacc[base * 32 + col] * w;
  }
  attb[(size_t)row * 256 + h * 32 + col] = f2b(o / L);
}

// ---------------- residual + LayerNorm (wave per row) ----------------
__global__ __launch_bounds__(256) void k_ln(const float* __restrict__ ina, const float* __restrict__ inb,
                                            const float* __restrict__ g, const float* __restrict__ b,
                                            float* __restrict__ outF, u16* __restrict__ outB){
  int t = threadIdx.x;
  int wv = t >> 6, lane = t & 63;
  int row = blockIdx.x * 4 + wv;
  size_t base = (size_t)row * CC + lane * 4;
  float4 xa = *(const float4*)&ina[base];
  float4 xb = *(const float4*)&inb[base];
  float v0 = xa.x + xb.x, v1 = xa.y + xb.y, v2 = xa.z + xb.z, v3 = xa.w + xb.w;
  float s  = v0 + v1 + v2 + v3;
  float s2 = v0*v0 + v1*v1 + v2*v2 + v3*v3;
  #pragma unroll
  for (int m = 1; m < 64; m <<= 1){
    s  += __shfl_xor(s,  m, 64);
    s2 += __shfl_xor(s2, m, 64);
  }
  float mu  = s * (1.0f / 256.0f);
  float var = s2 * (1.0f / 256.0f) - mu * mu;
  float rs  = rsqrtf(var + 1e-5f);
  float4 gv = *(const float4*)&g[lane * 4];
  float4 bv = *(const float4*)&b[lane * 4];
  float o0 = (v0 - mu) * rs * gv.x + bv.x;
  float o1 = (v1 - mu) * rs * gv.y + bv.y;
  float o2 = (v2 - mu) * rs * gv.z + bv.z;
  float o3 = (v3 - mu) * rs * gv.w + bv.w;
  if (outF){ float4 o = {o0, o1, o2, o3}; *(float4*)&outF[base] = o; }
  if (outB){
    outB[base+0] = f2b(o0); outB[base+1] = f2b(o1);
    outB[base+2] = f2b(o2); outB[base+3] = f2b(o3);
  }
}

// ---------------- launch ----------------
extern "C" void kernel_launch(void* const* d_in, const int* in_sizes, int n_in,
                              void* d_out, int out_size, void* d_ws, size_t ws_size,
                              hipStream_t stream){
  const float* x    = (const float*)d_in[0];
  const int*   ei   = (const int*)  d_in[1];
  const float* demb = (const float*)d_in[2];
  const float* spa  = (const float*)d_in[3];
  const float* Wq   = (const float*)d_in[4];
  const float* bq   = (const float*)d_in[5];
  const float* Wk   = (const float*)d_in[6];
  const float* bk   = (const float*)d_in[7];
  const float* Wv   = (const float*)d_in[8];
  const float* bv   = (const float*)d_in[9];
  const float* Wo   = (const float*)d_in[10];
  const float* bo   = (const float*)d_in[11];
  const float* g1   = (const float*)d_in[12];
  const float* b1   = (const float*)d_in[13];
  const float* g2   = (const float*)d_in[14];
  const float* b2   = (const float*)d_in[15];
  const float* Wf1  = (const float*)d_in[16];
  const float* bf1  = (const float*)d_in[17];
  const float* Wf2  = (const float*)d_in[18];
  const float* bf2  = (const float*)d_in[19];

  char* ws = (char*)d_ws;
  size_t off = 0;
  auto take = [&](size_t bytes)->char*{
    char* p = ws + off;
    off = (off + bytes + 255) & ~(size_t)255;
    return p;
  };
  int* deg    = (int*)take(4096 * 4);
  int* rowp   = (int*)take(4097 * 4);
  int* cur    = (int*)take(4096 * 4);
  int* col    = (int*)take(131072 * 4);
  u16* hid    = (u16*)take(2097152);
  u16* Wqkvt  = (u16*)take(768 * 256 * 2);
  u16* Wot    = (u16*)take(131072);
  u16* Wf1t   = (u16*)take(262144);
  u16* Wf2t   = (u16*)take(262144);
  float* bcat = (float*)take(768 * 4);
  u16* qkv    = (u16*)take(4194304);        // [4096][512] Q|K bf16
  u16* vt     = (u16*)take(2097152);        // [256][4096] V transposed
  u16* attb   = (u16*)take(2097152);
  char* SC    = take(18 * 1048576);         // BFS / attn partials / post-attn scratch
  u8* dist    = (u8*)take(16777216);
  u64* B[5];
  for (int i = 0; i < 5; i++) B[i] = (u64*)(SC + (size_t)i * 2097152);
  float* pacc    = (float*)SC;                       // 16 MB (B dead after k_dist)
  float* pml     = (float*)(SC + 16777216);          // 1 MB
  float* attnout = (float*)SC;                       // 4 MB (pacc dead after merge)
  float* hf      = (float*)(SC + 4194304);           // 4 MB
  u16*   hbf     = (u16*)  (SC + 8388608);           // 2 MB
  u16*   ff1     = (u16*)  dist;                     // 4 MB (dist dead after attn)
  float* ff2     = (float*)(dist + 8388608);         // 4 MB
  float* outp    = (float*)d_out;

  hipMemsetAsync(deg, 0, 4096 * 4, stream);
  k_deg   <<<256,  256, 0, stream>>>(ei, deg);
  k_scan  <<<1,    256, 0, stream>>>(deg, rowp, cur);
  k_fill  <<<256,  256, 0, stream>>>(ei, cur, col);
  k_hidden<<<4096, 256, 0, stream>>>(x, demb, deg, hid);
  k_b0    <<<1024, 256, 0, stream>>>(B[0]);
  for (int d = 0; d < 4; d++)
    k_prop<<<1024, 256, 0, stream>>>(B[d], B[d + 1], rowp, col);
  k_dist  <<<1024, 256, 0, stream>>>(B[1], B[2], B[3], B[4], dist);

  k_tconv<<<dim3(8, 8, 6), 256, 0, stream>>>(Wq, Wk, Wv, Wo, Wf1, Wf2,
                                             Wqkvt, Wqkvt + 256*256, Wqkvt + 512*256,
                                             Wot, Wf1t, Wf2t);
  k_bcat <<<3, 256, 0, stream>>>(bq, bk, bv, bcat);

  // fused QKV: N=768; cols [0,512) -> qkv row-major (stride 512), cols [512,768) -> vt transposed
  k_gemm32<<<dim3(128, 12), 256, 0, stream>>>(hid, Wqkvt, bcat, nullptr, qkv, vt,
                                              4096, 768, 256, 512, 2);

  k_attn <<<dim3(128, 2, 4), 256, 0, stream>>>(qkv, qkv + 256, 512, vt, dist, spa, pacc, pml);
  k_merge<<<4096, 256, 0, stream>>>(pacc, pml, attb);

  k_gemm32<<<dim3(128, 4), 256, 0, stream>>>(attb, Wot, bo, attnout, nullptr, nullptr,
                                             4096, 256, 256, 256, 1);
  k_ln   <<<1024, 256, 0, stream>>>(x, attnout, g1, b1, hf, hbf);
  k_gemm32<<<dim3(128, 8), 256, 0, stream>>>(hbf, Wf1t, bf1, nullptr, ff1, nullptr,
                                             4096, 512, 256, 512, 2 | 8);
  k_gemm32<<<dim3(128, 4), 256, 0, stream>>>(ff1, Wf2t, bf2, ff2, nullptr, nullptr,
                                             4096, 256, 512, 256, 1);
  k_ln   <<<1024, 256, 0, stream>>>(hf, ff2, g2, b2, outp, nullptr);
}